// Round 1
// 796.124 us; speedup vs baseline: 1.1154x; 1.1154x over previous
//
#include <hip/hip_runtime.h>

// ---------------------------------------------------------------------------
// Attention_89361089560777: B=8, S=1024, H=768, nh=12, d=64
// Pipeline: prep_weights, prep_h -> qkv_gemm(128x128,m97) -> vtrans ->
//           attn (all-heads-per-block, ASYNC16 LDS bias double-buffer) -> out_gemm
// R1: bias staging via global_load_lds double-buffer (was: register prefetch
//     that spilled ~390 MB/dispatch to scratch — WRITE_SIZE 378 MB anomaly).
// ---------------------------------------------------------------------------

typedef __attribute__((ext_vector_type(8))) __bf16 bf16x8;
typedef __attribute__((ext_vector_type(4))) float floatx4;
using bf16 = __bf16;

#define HID 768
#define NHEAD 12
#define DHEAD 64
#define SEQ 1024
#define NBATCH 8
#define WELEM (HID * HID)                      // 589824
#define QKVELEM (NBATCH * NHEAD * SEQ * DHEAD) // 6291456

__device__ __forceinline__ floatx4 mfma_bf16(bf16x8 a, bf16x8 b, floatx4 c) {
  return __builtin_amdgcn_mfma_f32_16x16x32_bf16(a, b, c, 0, 0, 0);
}

// async global->LDS, 16B per lane; LDS dest must be wave-uniform base + lane*16
#define ASYNC16(gp, lp)                                           \
  __builtin_amdgcn_global_load_lds(                               \
      (__attribute__((address_space(1))) void*)(gp),              \
      (__attribute__((address_space(3))) void*)(lp), 16, 0, 0)

// ---------------------------------------------------------------------------
// Weight prep: WT[m][n][k] = bf16(W_m[k][n])
// ---------------------------------------------------------------------------
__global__ void prep_weights(const float* __restrict__ Wq, const float* __restrict__ Wk,
                             const float* __restrict__ Wv, const float* __restrict__ Wo,
                             bf16* __restrict__ WT) {
  __shared__ float t[32][33];
  const int m = blockIdx.z;
  const float* W = (m == 0) ? Wq : (m == 1) ? Wk : (m == 2) ? Wv : Wo;
  const int k0 = blockIdx.x * 32, n0 = blockIdx.y * 32;
  const int tx = threadIdx.x, ty = threadIdx.y;
#pragma unroll
  for (int i = 0; i < 4; ++i)
    t[ty + 8 * i][tx] = W[(size_t)(k0 + ty + 8 * i) * HID + n0 + tx];
  __syncthreads();
  bf16* o = WT + (size_t)m * WELEM;
#pragma unroll
  for (int i = 0; i < 4; ++i)
    o[(size_t)(n0 + ty + 8 * i) * HID + k0 + tx] = (bf16)t[tx][ty + 8 * i];
}

// h (fp32) -> hb (bf16), 8 elems/thread
__global__ void prep_h(const float* __restrict__ X, bf16* __restrict__ Y) {
  const size_t i = ((size_t)blockIdx.x * 256 + threadIdx.x) * 8;
  float4 a = *(const float4*)(X + i);
  float4 b = *(const float4*)(X + i + 4);
  bf16x8 o;
  o[0] = (bf16)a.x; o[1] = (bf16)a.y; o[2] = (bf16)a.z; o[3] = (bf16)a.w;
  o[4] = (bf16)b.x; o[5] = (bf16)b.y; o[6] = (bf16)b.z; o[7] = (bf16)b.w;
  *(bf16x8*)(Y + i) = o;
}

// ---------------------------------------------------------------------------
// QKV GEMM, m97 structure: 128x128 tile, BK=32, global_load_lds w16.
// A = hb [8192][768] bf16, B = WT[mat] [n][k] bf16.
// mat0 -> Qb [b,h,s,d]*0.125 ; mat1 -> Kb [b,h,s,d] ; mat2 -> Vb [b,h,s,d]
// ---------------------------------------------------------------------------
__launch_bounds__(256, 2)
__global__ void qkv_gemm(const bf16* __restrict__ A, const bf16* __restrict__ WT,
                         const float* __restrict__ bq, const float* __restrict__ bk,
                         const float* __restrict__ bv,
                         bf16* __restrict__ Qb, bf16* __restrict__ Kb,
                         bf16* __restrict__ Vb) {
  __shared__ __align__(16) bf16 As[128][32];
  __shared__ __align__(16) bf16 Bs[128][32];
  const int mat = blockIdx.z;
  const int bn = blockIdx.x * 128, bm = blockIdx.y * 128;
  const bf16* W = WT + (size_t)mat * WELEM;
  const int tid = threadIdx.x, lane = tid & 63, warp = tid >> 6;
  const int fr = lane & 15, quad = lane >> 4;
  const int wr = warp >> 1, wc = warp & 1;

  floatx4 acc[4][4] = {};

  const int srow = tid >> 2, scol = (tid & 3) * 8;
  const bf16* as0 = A + (size_t)(bm + srow) * HID + scol;
  const bf16* as1 = A + (size_t)(bm + 64 + srow) * HID + scol;
  const bf16* bs0 = W + (size_t)(bn + srow) * HID + scol;
  const bf16* bs1 = W + (size_t)(bn + 64 + srow) * HID + scol;
  bf16* la0 = &As[srow][scol];
  bf16* la1 = &As[64 + srow][scol];
  bf16* lb0 = &Bs[srow][scol];
  bf16* lb1 = &Bs[64 + srow][scol];

  for (int k0 = 0; k0 < HID; k0 += 32) {
    ASYNC16(as0 + k0, la0);
    ASYNC16(as1 + k0, la1);
    ASYNC16(bs0 + k0, lb0);
    ASYNC16(bs1 + k0, lb1);
    __syncthreads();
    bf16x8 a[4], b[4];
#pragma unroll
    for (int mi = 0; mi < 4; ++mi) a[mi] = *(const bf16x8*)&As[wr * 64 + mi * 16 + fr][quad * 8];
#pragma unroll
    for (int ni = 0; ni < 4; ++ni) b[ni] = *(const bf16x8*)&Bs[wc * 64 + ni * 16 + fr][quad * 8];
#pragma unroll
    for (int mi = 0; mi < 4; ++mi)
#pragma unroll
      for (int ni = 0; ni < 4; ++ni) acc[mi][ni] = mfma_bf16(a[mi], b[ni], acc[mi][ni]);
    __syncthreads();
  }

  const float* bias = (mat == 0) ? bq : (mat == 1) ? bk : bv;
#pragma unroll
  for (int mi = 0; mi < 4; ++mi)
#pragma unroll
    for (int ni = 0; ni < 4; ++ni)
#pragma unroll
      for (int r = 0; r < 4; ++r) {
        const int grow = bm + wr * 64 + mi * 16 + quad * 4 + r;
        const int gcol = bn + wc * 64 + ni * 16 + fr;
        float v = acc[mi][ni][r] + bias[gcol];
        const int bb = grow >> 10, ss = grow & 1023;
        const int head = gcol >> 6, dc = gcol & 63;
        const size_t bh = (size_t)bb * NHEAD + head;
        const size_t idx = (bh * SEQ + ss) * DHEAD + dc;
        if (mat == 0) Qb[idx] = (bf16)(v * 0.125f);
        else if (mat == 1) Kb[idx] = (bf16)v;
        else Vb[idx] = (bf16)v;
      }
}

// ---------------------------------------------------------------------------
// V transpose: Vb [bh][s][d] -> Vt [bh][d][s], 64x64 LDS tiles
// ---------------------------------------------------------------------------
__global__ void vtrans(const bf16* __restrict__ Vb, bf16* __restrict__ Vt) {
  __shared__ bf16 t[64][72];
  const int st = blockIdx.x, bh = blockIdx.y;
  const int tid = threadIdx.x;
  const bf16* src = Vb + ((size_t)bh * SEQ + st * 64) * DHEAD;
#pragma unroll
  for (int p = 0; p < 2; ++p) {
    const int r = p * 32 + (tid >> 3), c = (tid & 7) * 8;
    *(bf16x8*)&t[r][c] = *(const bf16x8*)(src + (size_t)r * DHEAD + c);
  }
  __syncthreads();
#pragma unroll
  for (int p = 0; p < 2; ++p) {
    const int d = p * 32 + (tid >> 3), s0 = (tid & 7) * 8;
    bf16x8 o;
#pragma unroll
    for (int k = 0; k < 8; ++k) o[k] = t[s0 + k][d];
    *(bf16x8*)(Vt + ((size_t)bh * DHEAD + d) * SEQ + st * 64 + s0) = o;
  }
}

// ---------------------------------------------------------------------------
// Attention: block = (qt, b), 16 q-rows, ALL 12 heads (3 per wave).
// k-chunks of 32 with online softmax.
// Bias slab [16][32][12] fp32 staged straight into LDS with ASYNC16
// (global_load_lds) — double-buffered, no VGPR round trip, no spills.
// Mask prefetched to regs (8 ints). One barrier per chunk: the compiler's
// vmcnt(0)-before-s_barrier drain guarantees the async loads for chunk ch+1
// have landed by the time the buffer swap happens.
// P never leaves registers between softmax and PV.
// ---------------------------------------------------------------------------
__launch_bounds__(256, 2)
__global__ void attn_kernel(const bf16* __restrict__ Qb, const bf16* __restrict__ Kb,
                            const bf16* __restrict__ Vt, const float* __restrict__ bias,
                            const int* __restrict__ maskp, bf16* __restrict__ Ob) {
  __shared__ __align__(16) float Bb[2][16 * 32 * 12]; // bias double-buffer, 36 KB
  __shared__ __align__(16) float Sc[NHEAD][16][36];   // scores, padded, 27.6 KB
  // total LDS = 64512 B -> still 2 blocks/CU

  const int qt = blockIdx.x, b = blockIdx.y;
  const int tid = threadIdx.x, lane = tid & 63, warp = tid >> 6;
  const int fr = lane & 15, quad = lane >> 4;
  const size_t brow = (size_t)b * SEQ + qt * 16;  // global q-row base

  // Q fragments for this wave's 3 heads (pre-scaled by 1/8 in qkv_gemm)
  bf16x8 qa0[3], qa1[3];
#pragma unroll
  for (int j = 0; j < 3; ++j) {
    const size_t bh = (size_t)b * NHEAD + 3 * warp + j;
    const bf16* Qp = Qb + (bh * SEQ + qt * 16) * DHEAD;
    qa0[j] = *(const bf16x8*)(Qp + fr * DHEAD + quad * 8);
    qa1[j] = *(const bf16x8*)(Qp + fr * DHEAD + 32 + quad * 8);
  }

  float mrun[3] = {-1e30f, -1e30f, -1e30f};
  float lrun[3] = {0.f, 0.f, 0.f};
  floatx4 oacc[3][4] = {};

  const float4* biasf4 = (const float4*)bias;

  // ---- chunk 0 staging: bias -> LDS (async), mask -> regs ----
  int mreg[8];
  {
#pragma unroll
    for (int i = 0; i < 6; ++i) {
      const int f = tid + 256 * i, q = f / 96, rem = f % 96;
      ASYNC16(biasf4 + ((brow + q) * SEQ + 0) * 3 + rem, (float4*)Bb[0] + f);
    }
#pragma unroll
    for (int ct = 0; ct < 2; ++ct)
#pragma unroll
      for (int r = 0; r < 4; ++r)
        mreg[ct * 4 + r] = maskp[(brow + quad * 4 + r) * SEQ + ct * 16 + fr];
  }
  __syncthreads();  // drains vmcnt -> Bb[0] ready

  for (int ch = 0; ch < 32; ++ch) {
    const int c0 = ch * 32;
    const float* Bc = Bb[ch & 1];

    // ---- issue async staging of chunk ch+1 (overlaps with this chunk's compute) ----
    int mnext[8];
    if (ch < 31) {
      const int cn = c0 + 32;
      float* Bn = Bb[(ch + 1) & 1];
#pragma unroll
      for (int i = 0; i < 6; ++i) {
        const int f = tid + 256 * i, q = f / 96, rem = f % 96;
        ASYNC16(biasf4 + ((brow + q) * SEQ + cn) * 3 + rem, (float4*)Bn + f);
      }
#pragma unroll
      for (int ct = 0; ct < 2; ++ct)
#pragma unroll
        for (int r = 0; r < 4; ++r)
          mnext[ct * 4 + r] = maskp[(brow + quad * 4 + r) * SEQ + cn + ct * 16 + fr];
    }

    // ---- scores: QK^T + bias, mask -> Sc (C-layout scatter) ----
#pragma unroll
    for (int ct = 0; ct < 2; ++ct) {
#pragma unroll
      for (int j = 0; j < 3; ++j) {
        const int hh = 3 * warp + j;
        const size_t bh = (size_t)b * NHEAD + hh;
        const bf16* kp = Kb + (bh * SEQ + c0 + ct * 16 + fr) * DHEAD;
        bf16x8 kb0 = *(const bf16x8*)(kp + quad * 8);
        bf16x8 kb1 = *(const bf16x8*)(kp + 32 + quad * 8);
        floatx4 st = {0.f, 0.f, 0.f, 0.f};
        st = mfma_bf16(qa0[j], kb0, st);
        st = mfma_bf16(qa1[j], kb1, st);
#pragma unroll
        for (int r = 0; r < 4; ++r) {
          const float bvl = Bc[((quad * 4 + r) * 32 + ct * 16 + fr) * 12 + hh];
          Sc[hh][quad * 4 + r][ct * 16 + fr] = mreg[ct * 4 + r] ? 0.0f : (st[r] + bvl);
        }
      }
    }

    // ---- per-head online softmax (row = fr, cols quad*8..) + PV ----
#pragma unroll
    for (int j = 0; j < 3; ++j) {
      const int hh = 3 * warp + j;
      float4 sa = *(const float4*)&Sc[hh][fr][quad * 8];
      float4 sb = *(const float4*)&Sc[hh][fr][quad * 8 + 4];
      float s[8] = {sa.x, sa.y, sa.z, sa.w, sb.x, sb.y, sb.z, sb.w};
      float mx = mrun[j];
#pragma unroll
      for (int k = 0; k < 8; ++k) mx = fmaxf(mx, s[k]);
      mx = fmaxf(mx, __shfl_xor(mx, 16));
      mx = fmaxf(mx, __shfl_xor(mx, 32));
      const float alpha = __expf(mrun[j] - mx);
      float e[8], sum = 0.f;
#pragma unroll
      for (int k = 0; k < 8; ++k) { e[k] = __expf(s[k] - mx); sum += e[k]; }
      sum += __shfl_xor(sum, 16);
      sum += __shfl_xor(sum, 32);
      lrun[j] = lrun[j] * alpha + sum;
      mrun[j] = mx;
      bf16x8 pa;
#pragma unroll
      for (int k = 0; k < 8; ++k) pa[k] = (bf16)e[k];
      float ar[4];
#pragma unroll
      for (int r = 0; r < 4; ++r) ar[r] = __shfl(alpha, quad * 4 + r);
      const size_t bh = (size_t)b * NHEAD + hh;
#pragma unroll
      for (int dvt = 0; dvt < 4; ++dvt) {
#pragma unroll
        for (int r = 0; r < 4; ++r) oacc[j][dvt][r] *= ar[r];
        const bf16* vp = Vt + (bh * DHEAD + dvt * 16 + fr) * SEQ + c0 + quad * 8;
        bf16x8 vb = *(const bf16x8*)vp;
        oacc[j][dvt] = mfma_bf16(pa, vb, oacc[j][dvt]);
      }
    }

    // one barrier per chunk: all waves done reading Bb[cur]/Sc, and the
    // compiler-inserted vmcnt(0) drain makes Bb[nxt] (async loads) visible.
    __syncthreads();
    if (ch < 31) {
#pragma unroll
      for (int i = 0; i < 8; ++i) mreg[i] = mnext[i];
    }
  }

  // ---- epilogue: O / l -> Ob [b][s][hh*64+dv] ----
#pragma unroll
  for (int j = 0; j < 3; ++j) {
    const int hh = 3 * warp + j;
    const float linv = 1.0f / lrun[j];
    float lr[4];
#pragma unroll
    for (int r = 0; r < 4; ++r) lr[r] = __shfl(linv, quad * 4 + r);
#pragma unroll
    for (int dvt = 0; dvt < 4; ++dvt)
#pragma unroll
      for (int r = 0; r < 4; ++r)
        Ob[(brow + quad * 4 + r) * HID + hh * 64 + dvt * 16 + fr] =
            (bf16)(oacc[j][dvt][r] * lr[r]);
  }
}

// ---------------------------------------------------------------------------
// Output projection, m97 structure: out = Ob @ Wo + bo (fp32)
// ---------------------------------------------------------------------------
__launch_bounds__(256, 2)
__global__ void out_gemm(const bf16* __restrict__ A, const bf16* __restrict__ W,
                         const float* __restrict__ bo, float* __restrict__ out) {
  __shared__ __align__(16) bf16 As[128][32];
  __shared__ __align__(16) bf16 Bs[128][32];
  const int bn = blockIdx.x * 128, bm = blockIdx.y * 128;
  const int tid = threadIdx.x, lane = tid & 63, warp = tid >> 6;
  const int fr = lane & 15, quad = lane >> 4;
  const int wr = warp >> 1, wc = warp & 1;

  floatx4 acc[4][4] = {};

  const int srow = tid >> 2, scol = (tid & 3) * 8;
  const bf16* as0 = A + (size_t)(bm + srow) * HID + scol;
  const bf16* as1 = A + (size_t)(bm + 64 + srow) * HID + scol;
  const bf16* bs0 = W + (size_t)(bn + srow) * HID + scol;
  const bf16* bs1 = W + (size_t)(bn + 64 + srow) * HID + scol;
  bf16* la0 = &As[srow][scol];
  bf16* la1 = &As[64 + srow][scol];
  bf16* lb0 = &Bs[srow][scol];
  bf16* lb1 = &Bs[64 + srow][scol];

  for (int k0 = 0; k0 < HID; k0 += 32) {
    ASYNC16(as0 + k0, la0);
    ASYNC16(as1 + k0, la1);
    ASYNC16(bs0 + k0, lb0);
    ASYNC16(bs1 + k0, lb1);
    __syncthreads();
    bf16x8 a[4], b[4];
#pragma unroll
    for (int mi = 0; mi < 4; ++mi) a[mi] = *(const bf16x8*)&As[wr * 64 + mi * 16 + fr][quad * 8];
#pragma unroll
    for (int ni = 0; ni < 4; ++ni) b[ni] = *(const bf16x8*)&Bs[wc * 64 + ni * 16 + fr][quad * 8];
#pragma unroll
    for (int mi = 0; mi < 4; ++mi)
#pragma unroll
      for (int ni = 0; ni < 4; ++ni) acc[mi][ni] = mfma_bf16(a[mi], b[ni], acc[mi][ni]);
    __syncthreads();
  }

#pragma unroll
  for (int mi = 0; mi < 4; ++mi)
#pragma unroll
    for (int ni = 0; ni < 4; ++ni)
#pragma unroll
      for (int r = 0; r < 4; ++r) {
        const int grow = bm + wr * 64 + mi * 16 + quad * 4 + r;
        const int gcol = bn + wc * 64 + ni * 16 + fr;
        out[(size_t)grow * HID + gcol] = acc[mi][ni][r] + bo[gcol];
      }
}

// ---------------------------------------------------------------------------
extern "C" void kernel_launch(void* const* d_in, const int* in_sizes, int n_in,
                              void* d_out, int out_size, void* d_ws, size_t ws_size,
                              hipStream_t stream) {
  const float* h  = (const float*)d_in[0];
  const float* ab = (const float*)d_in[1];
  const int*   mk = (const int*)d_in[2];
  const float* Wq = (const float*)d_in[3];
  const float* bq = (const float*)d_in[4];
  const float* Wk = (const float*)d_in[5];
  const float* bk = (const float*)d_in[6];
  const float* Wv = (const float*)d_in[7];
  const float* bv = (const float*)d_in[8];
  const float* Wo = (const float*)d_in[9];
  const float* bo = (const float*)d_in[10];
  float* out = (float*)d_out;

  // ws (bf16): WT[4*W] | hb | Qb | Kb | Vb | Vt ; Ob reuses Vb (dead after vtrans)
  bf16* WT = (bf16*)d_ws;
  bf16* hb = WT + (size_t)4 * WELEM;
  bf16* Qb = hb + (size_t)QKVELEM;
  bf16* Kb = Qb + (size_t)QKVELEM;
  bf16* Vb = Kb + (size_t)QKVELEM;
  bf16* Vt = Vb + (size_t)QKVELEM;
  bf16* Ob = Vb;  // reuse

  prep_weights<<<dim3(24, 24, 4), dim3(32, 8), 0, stream>>>(Wq, Wk, Wv, Wo, WT);
  prep_h<<<3072, 256, 0, stream>>>(h, hb);
  qkv_gemm<<<dim3(6, 64, 3), 256, 0, stream>>>(hb, WT, bq, bk, bv, Qb, Kb, Vb);
  vtrans<<<dim3(16, 96), 256, 0, stream>>>(Vb, Vt);
  attn_kernel<<<dim3(64, 8), 256, 0, stream>>>(Qb, Kb, Vt, ab, mk, Ob);
  out_gemm<<<dim3(6, 64), 256, 0, stream>>>(Ob, WT + (size_t)3 * WELEM, bo, out);
}